// Round 4
// baseline (1001.944 us; speedup 1.0000x reference)
//
#include <hip/hip_runtime.h>

// DCRNN (DCE'd): 65536 independent sequences, 12 steps, 2-layer GRU-lite, H=64.
// fp32 vector-ALU implementation (no fp32 MFMA on CDNA4).
//
// Block: 256 threads, 64 sequences. Thread tile: 4 seqs x 4 cols, u+c gates
// (32 accumulators). h-state in LDS [64][132] (pad -> 2-way bank alias = free).
// Weights packed in d_ws, streamed from global (L2 broadcast) with a manual
// 2-deep register double-buffer; biases/Wo staged in LDS (they were being
// spilled to scratch in round 2: WRITE_SIZE 17.6MB, VGPR=64).
// amdgpu_waves_per_eu(4,4): LDS caps at 4 blocks/CU anyway -> let regalloc
// use up to 128 VGPRs.

#define TSTEPS 12
#define SEQ 64
#define AROW 132

__device__ __forceinline__ float fsig(float z) {
    z = fminf(fmaxf(z, -30.f), 30.f);
    return 1.f / (1.f + __expf(-z));
}
__device__ __forceinline__ float ftanh(float z) {
    z = fminf(fmaxf(z, -15.f), 15.f);
    float e = __expf(2.f * z);
    return 1.f - 2.f / (e + 1.f);
}

// ---- workspace layout (floats) ----
// [0, 256)          W0x  : 64 float4 (Wu0[0][c], Wu0[1][c], Wc0[0][c], Wc0[1][c])
// [256, 8448)       W0h  : 16 k4-rows x 128 float4  [u cols | c cols]
// [8448, 8960)      pad  : 1 zero k4-row (prefetch guard)
// [8960, 25344)     W1h  : 32 k4-rows x 128 float4
// [25344, 25856)    pad  : 1 zero k4-row (prefetch guard)
// [25856, 25984)    bu0 | bc0
// [25984, 26112)    bu1 | bc1
// [26112, 26176)    Wo
// [26176]           bo

__global__ void pack_weights(const float* __restrict__ Wu0, const float* __restrict__ bu0,
                             const float* __restrict__ Wc0, const float* __restrict__ bc0,
                             const float* __restrict__ Wu1, const float* __restrict__ bu1,
                             const float* __restrict__ Wc1, const float* __restrict__ bc1,
                             const float* __restrict__ Wo, const float* __restrict__ bo,
                             float* __restrict__ Wp) {
    const int tid = blockIdx.x * blockDim.x + threadIdx.x;
    const int nthr = gridDim.x * blockDim.x;
    float4* W0x = (float4*)Wp;
    float4* W0h = (float4*)(Wp + 256);
    float4* W1h = (float4*)(Wp + 8960);

    if (tid < 64) {
        W0x[tid] = make_float4(Wu0[tid], Wu0[64 + tid], Wc0[tid], Wc0[64 + tid]);
    }
    for (int i = tid; i < 16 * 128; i += nthr) {
        const int k4 = i >> 7, col = i & 127;
        const float* G = (col < 64) ? Wu0 : Wc0;
        const int cc = col & 63;
        const int r = 2 + k4 * 4;
        W0h[i] = make_float4(G[r * 64 + cc], G[(r + 1) * 64 + cc],
                             G[(r + 2) * 64 + cc], G[(r + 3) * 64 + cc]);
    }
    for (int i = tid; i < 32 * 128; i += nthr) {
        const int k4 = i >> 7, col = i & 127;
        const float* G = (col < 64) ? Wu1 : Wc1;
        const int cc = col & 63;
        const int r = k4 * 4;
        W1h[i] = make_float4(G[r * 64 + cc], G[(r + 1) * 64 + cc],
                             G[(r + 2) * 64 + cc], G[(r + 3) * 64 + cc]);
    }
    // zero prefetch-guard rows
    for (int i = tid; i < 512; i += nthr) { Wp[8448 + i] = 0.f; Wp[25344 + i] = 0.f; }
    if (tid < 128) Wp[25856 + tid] = (tid < 64) ? bu0[tid] : bc0[tid - 64];
    if (tid >= 128 && tid < 256) {
        const int q = tid - 128;
        Wp[25984 + q] = (q < 64) ? bu1[q] : bc1[q - 64];
    }
    if (tid >= 256 && tid < 320) Wp[26112 + (tid - 256)] = Wo[tid - 256];
    if (tid == 320) Wp[26176] = bo[0];
}

__device__ __forceinline__ void accum4x4(float aU[4][4], float aC[4][4],
                                         const float4 a4[4],
                                         const float4 wu[4], const float4 wc[4]) {
#pragma unroll
    for (int m = 0; m < 4; ++m)
#pragma unroll
        for (int j = 0; j < 4; ++j) {
            aU[m][j] += a4[m].x * wu[j].x; aU[m][j] += a4[m].y * wu[j].y;
            aU[m][j] += a4[m].z * wu[j].z; aU[m][j] += a4[m].w * wu[j].w;
            aC[m][j] += a4[m].x * wc[j].x; aC[m][j] += a4[m].y * wc[j].y;
            aC[m][j] += a4[m].z * wc[j].z; aC[m][j] += a4[m].w * wc[j].w;
        }
}

__global__ __attribute__((amdgpu_flat_work_group_size(256, 256),
                          amdgpu_waves_per_eu(4, 4)))
void dcrnn_main(const float* __restrict__ x,
                const float* __restrict__ Wp,
                float* __restrict__ out) {
    __shared__ float A[SEQ * AROW];   // [seq][0..63]=h0, [64..127]=h1, pad
    __shared__ float xs[SEQ * 2];
    __shared__ float bsh[324];        // bu0|bc0 (128) | bu1|bc1 (128) | Wo (64) | bo

    const int tid = threadIdx.x;
    const int sg = tid & 15;        // seq group: seqs sg, sg+16, sg+32, sg+48
    const int jg = tid >> 4;        // col group 0..15
    const int jcol = jg * 4;

    const int s0 = blockIdx.x * SEQ;
    const int b = s0 >> 11;
    const int n0 = s0 & 2047;

    const float4* W0x = (const float4*)Wp;
    const float4* W0h = (const float4*)(Wp + 256);
    const float4* W1h = (const float4*)(Wp + 8960);

    for (int i = tid; i < SEQ * AROW; i += 256) A[i] = 0.f;
    if (tid < 256) bsh[tid] = Wp[25856 + tid];
    if (tid < 65)  bsh[256 + tid] = Wp[26112 + tid];

    const float* xb = x + (size_t)(b * TSTEPS) * 4096 + (size_t)n0 * 2;

    int srow[4];
#pragma unroll
    for (int m = 0; m < 4; ++m) srow[m] = (sg + 16 * m) * AROW;

#pragma unroll 1
    for (int t = 0; t < TSTEPS; ++t) {
        if (tid < 32) ((float4*)xs)[tid] = ((const float4*)(xb + t * 4096))[tid];
        __syncthreads();  // (1) x staged; prev-step h writes + bsh visible

        // ================= layer 0 : [x|h0] @ {Wu0,Wc0} =================
        float aU[4][4], aC[4][4];
        {
            const float4 b0u = *(const float4*)&bsh[jcol];
            const float4 b0c = *(const float4*)&bsh[64 + jcol];
#pragma unroll
            for (int m = 0; m < 4; ++m) {
                aU[m][0] = b0u.x; aU[m][1] = b0u.y; aU[m][2] = b0u.z; aU[m][3] = b0u.w;
                aC[m][0] = b0c.x; aC[m][1] = b0c.y; aC[m][2] = b0c.z; aC[m][3] = b0c.w;
            }
        }
        {
            float4 wx[4];
#pragma unroll
            for (int j = 0; j < 4; ++j) wx[j] = W0x[jcol + j];
#pragma unroll
            for (int m = 0; m < 4; ++m) {
                const int s = sg + 16 * m;
                const float x0v = xs[2 * s], x1v = xs[2 * s + 1];
#pragma unroll
                for (int j = 0; j < 4; ++j) {
                    aU[m][j] += x0v * wx[j].x + x1v * wx[j].y;
                    aC[m][j] += x0v * wx[j].z + x1v * wx[j].w;
                }
            }
        }
        {
            const float4* wp = W0h + jcol;
            float4 wuA[4], wcA[4], wuB[4], wcB[4];
#pragma unroll
            for (int j = 0; j < 4; ++j) { wuA[j] = wp[j]; wcA[j] = wp[64 + j]; }
#pragma unroll 1
            for (int k4 = 0; k4 < 16; k4 += 2) {
#pragma unroll
                for (int j = 0; j < 4; ++j) { wuB[j] = wp[128 + j]; wcB[j] = wp[192 + j]; }
                float4 a4[4];
#pragma unroll
                for (int m = 0; m < 4; ++m) a4[m] = *(const float4*)&A[srow[m] + k4 * 4];
                accum4x4(aU, aC, a4, wuA, wcA);
                wp += 256;
#pragma unroll
                for (int j = 0; j < 4; ++j) { wuA[j] = wp[j]; wcA[j] = wp[64 + j]; }
#pragma unroll
                for (int m = 0; m < 4; ++m) a4[m] = *(const float4*)&A[srow[m] + k4 * 4 + 4];
                accum4x4(aU, aC, a4, wuB, wcB);
            }
        }
        float4 hn[4];
#pragma unroll
        for (int m = 0; m < 4; ++m) {
            float4 hold = *(const float4*)&A[srow[m] + jcol];
            float* hp = (float*)&hold;
            float* hq = (float*)&hn[m];
#pragma unroll
            for (int j = 0; j < 4; ++j) {
                const float u = fsig(aU[m][j]);
                const float c = ftanh(aC[m][j]);
                hq[j] = u * hp[j] + (1.f - u) * c;
            }
        }
        __syncthreads();  // (2) all reads of h0_old done
#pragma unroll
        for (int m = 0; m < 4; ++m) *(float4*)&A[srow[m] + jcol] = hn[m];
        __syncthreads();  // (3) h0_new visible

        // ================= layer 1 : [h0|h1] @ {Wu1,Wc1} =================
        {
            const float4 b1u = *(const float4*)&bsh[128 + jcol];
            const float4 b1c = *(const float4*)&bsh[192 + jcol];
#pragma unroll
            for (int m = 0; m < 4; ++m) {
                aU[m][0] = b1u.x; aU[m][1] = b1u.y; aU[m][2] = b1u.z; aU[m][3] = b1u.w;
                aC[m][0] = b1c.x; aC[m][1] = b1c.y; aC[m][2] = b1c.z; aC[m][3] = b1c.w;
            }
        }
        {
            const float4* wp = W1h + jcol;
            float4 wuA[4], wcA[4], wuB[4], wcB[4];
#pragma unroll
            for (int j = 0; j < 4; ++j) { wuA[j] = wp[j]; wcA[j] = wp[64 + j]; }
#pragma unroll 1
            for (int k4 = 0; k4 < 32; k4 += 2) {
#pragma unroll
                for (int j = 0; j < 4; ++j) { wuB[j] = wp[128 + j]; wcB[j] = wp[192 + j]; }
                float4 a4[4];
#pragma unroll
                for (int m = 0; m < 4; ++m) a4[m] = *(const float4*)&A[srow[m] + k4 * 4];
                accum4x4(aU, aC, a4, wuA, wcA);
                wp += 256;
#pragma unroll
                for (int j = 0; j < 4; ++j) { wuA[j] = wp[j]; wcA[j] = wp[64 + j]; }
#pragma unroll
                for (int m = 0; m < 4; ++m) a4[m] = *(const float4*)&A[srow[m] + k4 * 4 + 4];
                accum4x4(aU, aC, a4, wuB, wcB);
            }
        }
#pragma unroll
        for (int m = 0; m < 4; ++m) {
            float4 hold = *(const float4*)&A[srow[m] + 64 + jcol];
            float* hp = (float*)&hold;
            float* hq = (float*)&hn[m];
#pragma unroll
            for (int j = 0; j < 4; ++j) {
                const float u = fsig(aU[m][j]);
                const float c = ftanh(aC[m][j]);
                hq[j] = u * hp[j] + (1.f - u) * c;
            }
        }
        __syncthreads();  // (4) all reads of h1_old done
#pragma unroll
        for (int m = 0; m < 4; ++m) *(float4*)&A[srow[m] + 64 + jcol] = hn[m];
        // next-iteration barrier (1) makes h1_new visible before anyone reads it
    }

    __syncthreads();  // h1 final visible
    if (tid < 64) {
        float acc = bsh[320];
#pragma unroll
        for (int k4 = 0; k4 < 16; ++k4) {
            const float4 h4 = *(const float4*)&A[tid * AROW + 64 + k4 * 4];
            const float4 w4 = *(const float4*)&bsh[256 + k4 * 4];
            acc += h4.x * w4.x + h4.y * w4.y + h4.z * w4.z + h4.w * w4.w;
        }
        out[s0 + tid] = acc;
    }
}

extern "C" void kernel_launch(void* const* d_in, const int* in_sizes, int n_in,
                              void* d_out, int out_size, void* d_ws, size_t ws_size,
                              hipStream_t stream) {
    const float* x   = (const float*)d_in[0];
    // d_in[1] supports, d_in[2] Wr0, d_in[3] br0 : dead code in reference
    const float* Wu0 = (const float*)d_in[4];
    const float* bu0 = (const float*)d_in[5];
    const float* Wc0 = (const float*)d_in[6];
    const float* bc0 = (const float*)d_in[7];
    // d_in[8] Wd0, d_in[9] bd0, d_in[10] Wr1, d_in[11] br1 : dead
    const float* Wu1 = (const float*)d_in[12];
    const float* bu1 = (const float*)d_in[13];
    const float* Wc1 = (const float*)d_in[14];
    const float* bc1 = (const float*)d_in[15];
    // d_in[16] Wd1, d_in[17] bd1 : dead
    const float* Wo  = (const float*)d_in[18];
    const float* bo  = (const float*)d_in[19];

    float* Wp = (float*)d_ws;  // ~105 KB

    hipLaunchKernelGGL(pack_weights, dim3(2), dim3(256), 0, stream,
                       Wu0, bu0, Wc0, bc0, Wu1, bu1, Wc1, bc1, Wo, bo, Wp);
    hipLaunchKernelGGL(dcrnn_main, dim3(65536 / SEQ), dim3(256), 0, stream,
                       x, Wp, (float*)d_out);
}

// Round 5
// 806.163 us; speedup vs baseline: 1.2429x; 1.2429x over previous
//
#include <hip/hip_runtime.h>

// DCRNN (DCE'd): 65536 independent sequences, 12 steps, 2-layer GRU-lite, H=64.
// fp32 vector-ALU implementation (no fp32 MFMA on CDNA4).
//
// Round-5 change: FULLY SCALARIZED inner kernel. Rounds 2/4 showed VGPR=64 +
// 17-57 MB scratch traffic regardless of launch-bounds/waves-per-eu -> local
// arrays (accum4x4 array params, float* punning) were living in scratch, not
// registers. This version has ZERO local arrays in dcrnn_main: 32 named float
// accumulators, named float4 weight/activation temps, macro-expanded FMAs.
// Biases re-read from LDS each step (no long-lived bias regs).

#define TSTEPS 12
#define SEQ 64
#define AROW 132

__device__ __forceinline__ float fsig(float z) {
    z = fminf(fmaxf(z, -30.f), 30.f);
    return 1.f / (1.f + __expf(-z));
}
__device__ __forceinline__ float ftanh(float z) {
    z = fminf(fmaxf(z, -15.f), 15.f);
    float e = __expf(2.f * z);
    return 1.f - 2.f / (e + 1.f);
}

// ---- workspace layout (floats) ----
// [0, 256)          W0x  : 64 float4 (Wu0[0][c], Wu0[1][c], Wc0[0][c], Wc0[1][c])
// [256, 8448)       W0h  : 16 k4-rows x 128 float4  [u cols | c cols]
// [8448, 8960)      pad
// [8960, 25344)     W1h  : 32 k4-rows x 128 float4
// [25344, 25856)    pad
// [25856, 25984)    bu0 | bc0
// [25984, 26112)    bu1 | bc1
// [26112, 26176)    Wo
// [26176]           bo

__global__ void pack_weights(const float* __restrict__ Wu0, const float* __restrict__ bu0,
                             const float* __restrict__ Wc0, const float* __restrict__ bc0,
                             const float* __restrict__ Wu1, const float* __restrict__ bu1,
                             const float* __restrict__ Wc1, const float* __restrict__ bc1,
                             const float* __restrict__ Wo, const float* __restrict__ bo,
                             float* __restrict__ Wp) {
    const int tid = blockIdx.x * blockDim.x + threadIdx.x;
    const int nthr = gridDim.x * blockDim.x;
    float4* W0x = (float4*)Wp;
    float4* W0h = (float4*)(Wp + 256);
    float4* W1h = (float4*)(Wp + 8960);

    if (tid < 64) {
        W0x[tid] = make_float4(Wu0[tid], Wu0[64 + tid], Wc0[tid], Wc0[64 + tid]);
    }
    for (int i = tid; i < 16 * 128; i += nthr) {
        const int k4 = i >> 7, col = i & 127;
        const float* G = (col < 64) ? Wu0 : Wc0;
        const int cc = col & 63;
        const int r = 2 + k4 * 4;
        W0h[i] = make_float4(G[r * 64 + cc], G[(r + 1) * 64 + cc],
                             G[(r + 2) * 64 + cc], G[(r + 3) * 64 + cc]);
    }
    for (int i = tid; i < 32 * 128; i += nthr) {
        const int k4 = i >> 7, col = i & 127;
        const float* G = (col < 64) ? Wu1 : Wc1;
        const int cc = col & 63;
        const int r = k4 * 4;
        W1h[i] = make_float4(G[r * 64 + cc], G[(r + 1) * 64 + cc],
                             G[(r + 2) * 64 + cc], G[(r + 3) * 64 + cc]);
    }
    for (int i = tid; i < 512; i += nthr) { Wp[8448 + i] = 0.f; Wp[25344 + i] = 0.f; }
    if (tid < 128) Wp[25856 + tid] = (tid < 64) ? bu0[tid] : bc0[tid - 64];
    if (tid >= 128 && tid < 256) {
        const int q = tid - 128;
        Wp[25984 + q] = (q < 64) ? bu1[q] : bc1[q - 64];
    }
    if (tid >= 256 && tid < 320) Wp[26112 + (tid - 256)] = Wo[tid - 256];
    if (tid == 320) Wp[26176] = bo[0];
}

// ---- scalarized FMA machinery (no local arrays anywhere) ----
#define DOT4(acc, av, wv) { acc += av.x * wv.x; acc += av.y * wv.y; \
                            acc += av.z * wv.z; acc += av.w * wv.w; }

#define FMAROW(M, av) \
    DOT4(aU##M##0, av, w0) DOT4(aU##M##1, av, w1) DOT4(aU##M##2, av, w2) DOT4(aU##M##3, av, w3) \
    DOT4(aC##M##0, av, w4) DOT4(aC##M##1, av, w5) DOT4(aC##M##2, av, w6) DOT4(aC##M##3, av, w7)

#define KCHUNK(WQ, AOFF) { \
    const float4 w0 = (WQ)[0],  w1 = (WQ)[1],  w2 = (WQ)[2],  w3 = (WQ)[3]; \
    const float4 w4 = (WQ)[64], w5 = (WQ)[65], w6 = (WQ)[66], w7 = (WQ)[67]; \
    const float4 a0v = *(const float4*)&A[srow0 + (AOFF)]; \
    const float4 a1v = *(const float4*)&A[srow1 + (AOFF)]; \
    const float4 a2v = *(const float4*)&A[srow2 + (AOFF)]; \
    const float4 a3v = *(const float4*)&A[srow3 + (AOFF)]; \
    FMAROW(0, a0v) FMAROW(1, a1v) FMAROW(2, a2v) FMAROW(3, a3v) }

#define AINIT(BU_OFF, BC_OFF) { \
    const float4 bu = *(const float4*)&bsh[(BU_OFF) + jcol]; \
    const float4 bc = *(const float4*)&bsh[(BC_OFF) + jcol]; \
    aU00 = bu.x; aU01 = bu.y; aU02 = bu.z; aU03 = bu.w; \
    aU10 = bu.x; aU11 = bu.y; aU12 = bu.z; aU13 = bu.w; \
    aU20 = bu.x; aU21 = bu.y; aU22 = bu.z; aU23 = bu.w; \
    aU30 = bu.x; aU31 = bu.y; aU32 = bu.z; aU33 = bu.w; \
    aC00 = bc.x; aC01 = bc.y; aC02 = bc.z; aC03 = bc.w; \
    aC10 = bc.x; aC11 = bc.y; aC12 = bc.z; aC13 = bc.w; \
    aC20 = bc.x; aC21 = bc.y; aC22 = bc.z; aC23 = bc.w; \
    aC30 = bc.x; aC31 = bc.y; aC32 = bc.z; aC33 = bc.w; }

#define XPART(M) { \
    const int s_ = sg + 16 * M; \
    const float x0v = xs[2 * s_], x1v = xs[2 * s_ + 1]; \
    aU##M##0 += x0v * wx0.x + x1v * wx0.y;  aC##M##0 += x0v * wx0.z + x1v * wx0.w; \
    aU##M##1 += x0v * wx1.x + x1v * wx1.y;  aC##M##1 += x0v * wx1.z + x1v * wx1.w; \
    aU##M##2 += x0v * wx2.x + x1v * wx2.y;  aC##M##2 += x0v * wx2.z + x1v * wx2.w; \
    aU##M##3 += x0v * wx3.x + x1v * wx3.y;  aC##M##3 += x0v * wx3.z + x1v * wx3.w; }

#define HUPDATE(M, COLBASE) { \
    const float4 ho = *(const float4*)&A[srow##M + (COLBASE)]; \
    float u_, c_; \
    u_ = fsig(aU##M##0); c_ = ftanh(aC##M##0); hn##M.x = u_ * ho.x + (1.f - u_) * c_; \
    u_ = fsig(aU##M##1); c_ = ftanh(aC##M##1); hn##M.y = u_ * ho.y + (1.f - u_) * c_; \
    u_ = fsig(aU##M##2); c_ = ftanh(aC##M##2); hn##M.z = u_ * ho.z + (1.f - u_) * c_; \
    u_ = fsig(aU##M##3); c_ = ftanh(aC##M##3); hn##M.w = u_ * ho.w + (1.f - u_) * c_; }

__global__ __launch_bounds__(256, 4) void dcrnn_main(const float* __restrict__ x,
                                                     const float* __restrict__ Wp,
                                                     float* __restrict__ out) {
    __shared__ float A[SEQ * AROW];   // [seq][0..63]=h0, [64..127]=h1, pad
    __shared__ float xs[SEQ * 2];
    __shared__ float bsh[324];        // bu0|bc0 (128) | bu1|bc1 (128) | Wo (64) | bo

    const int tid = threadIdx.x;
    const int sg = tid & 15;        // seq group: seqs sg, sg+16, sg+32, sg+48
    const int jg = tid >> 4;        // col group 0..15
    const int jcol = jg * 4;

    const int s0 = blockIdx.x * SEQ;
    const int b = s0 >> 11;
    const int n0 = s0 & 2047;

    const float4* W0x = (const float4*)Wp;
    const float4* W0h = (const float4*)(Wp + 256);
    const float4* W1h = (const float4*)(Wp + 8960);

    for (int i = tid; i < SEQ * AROW; i += 256) A[i] = 0.f;
    bsh[tid] = Wp[25856 + tid];
    if (tid < 65) bsh[256 + tid] = Wp[26112 + tid];

    const float* xb = x + (size_t)(b * TSTEPS) * 4096 + (size_t)n0 * 2;

    const int srow0 = (sg + 0)  * AROW;
    const int srow1 = (sg + 16) * AROW;
    const int srow2 = (sg + 32) * AROW;
    const int srow3 = (sg + 48) * AROW;

    float aU00, aU01, aU02, aU03, aU10, aU11, aU12, aU13;
    float aU20, aU21, aU22, aU23, aU30, aU31, aU32, aU33;
    float aC00, aC01, aC02, aC03, aC10, aC11, aC12, aC13;
    float aC20, aC21, aC22, aC23, aC30, aC31, aC32, aC33;
    float4 hn0, hn1, hn2, hn3;

#pragma unroll 1
    for (int t = 0; t < TSTEPS; ++t) {
        if (tid < 32) ((float4*)xs)[tid] = ((const float4*)(xb + t * 4096))[tid];
        __syncthreads();  // (1) x staged; prev-step h writes (+ init) visible

        // ================= layer 0 : [x|h0] @ {Wu0,Wc0} =================
        AINIT(0, 64)
        {
            const float4 wx0 = W0x[jcol + 0], wx1 = W0x[jcol + 1];
            const float4 wx2 = W0x[jcol + 2], wx3 = W0x[jcol + 3];
            XPART(0) XPART(1) XPART(2) XPART(3)
        }
        {
            const float4* wq = W0h + jcol;
#pragma unroll 4
            for (int k4 = 0; k4 < 16; ++k4) {
                KCHUNK(wq, k4 * 4)
                wq += 128;
            }
        }
        HUPDATE(0, jcol) HUPDATE(1, jcol) HUPDATE(2, jcol) HUPDATE(3, jcol)
        __syncthreads();  // (2) all reads of h0_old done
        *(float4*)&A[srow0 + jcol] = hn0;
        *(float4*)&A[srow1 + jcol] = hn1;
        *(float4*)&A[srow2 + jcol] = hn2;
        *(float4*)&A[srow3 + jcol] = hn3;
        __syncthreads();  // (3) h0_new visible

        // ================= layer 1 : [h0|h1] @ {Wu1,Wc1} =================
        AINIT(128, 192)
        {
            const float4* wq = W1h + jcol;
#pragma unroll 4
            for (int k4 = 0; k4 < 32; ++k4) {
                KCHUNK(wq, k4 * 4)
                wq += 128;
            }
        }
        HUPDATE(0, 64 + jcol) HUPDATE(1, 64 + jcol) HUPDATE(2, 64 + jcol) HUPDATE(3, 64 + jcol)
        __syncthreads();  // (4) all reads of h1_old done
        *(float4*)&A[srow0 + 64 + jcol] = hn0;
        *(float4*)&A[srow1 + 64 + jcol] = hn1;
        *(float4*)&A[srow2 + 64 + jcol] = hn2;
        *(float4*)&A[srow3 + 64 + jcol] = hn3;
        // next-iteration barrier (1) makes h1_new visible before anyone reads it
    }

    __syncthreads();  // h1 final visible
    if (tid < 64) {
        float acc = bsh[320];
#pragma unroll
        for (int k4 = 0; k4 < 16; ++k4) {
            const float4 h4 = *(const float4*)&A[tid * AROW + 64 + k4 * 4];
            const float4 w4 = *(const float4*)&bsh[256 + k4 * 4];
            acc += h4.x * w4.x + h4.y * w4.y + h4.z * w4.z + h4.w * w4.w;
        }
        out[s0 + tid] = acc;
    }
}

extern "C" void kernel_launch(void* const* d_in, const int* in_sizes, int n_in,
                              void* d_out, int out_size, void* d_ws, size_t ws_size,
                              hipStream_t stream) {
    const float* x   = (const float*)d_in[0];
    // d_in[1] supports, d_in[2] Wr0, d_in[3] br0 : dead code in reference
    const float* Wu0 = (const float*)d_in[4];
    const float* bu0 = (const float*)d_in[5];
    const float* Wc0 = (const float*)d_in[6];
    const float* bc0 = (const float*)d_in[7];
    // d_in[8] Wd0, d_in[9] bd0, d_in[10] Wr1, d_in[11] br1 : dead
    const float* Wu1 = (const float*)d_in[12];
    const float* bu1 = (const float*)d_in[13];
    const float* Wc1 = (const float*)d_in[14];
    const float* bc1 = (const float*)d_in[15];
    // d_in[16] Wd1, d_in[17] bd1 : dead
    const float* Wo  = (const float*)d_in[18];
    const float* bo  = (const float*)d_in[19];

    float* Wp = (float*)d_ws;  // ~105 KB

    hipLaunchKernelGGL(pack_weights, dim3(2), dim3(256), 0, stream,
                       Wu0, bu0, Wc0, bc0, Wu1, bu1, Wc1, bc1, Wo, bo, Wp);
    hipLaunchKernelGGL(dcrnn_main, dim3(65536 / SEQ), dim3(256), 0, stream,
                       x, Wp, (float*)d_out);
}

// Round 6
// 765.418 us; speedup vs baseline: 1.3090x; 1.0532x over previous
//
#include <hip/hip_runtime.h>

// DCRNN (DCE'd): 65536 independent sequences, 12 steps, 2-layer GRU-lite, H=64.
// fp32 vector-ALU implementation (no fp32 MFMA on CDNA4).
//
// Round-6 change: force the register allocator to stop chasing 8 waves/EU.
// Round 5 (scalarized) still showed VGPR_Count=64 (=512/8: the 8-waves/EU
// budget) with ~1 extra VALU op per FMA and 7 MB scratch — the allocator
// sinks weight loads into load-use pairs to fit 64 regs, while occupancy is
// LDS/grid-capped at ~3-4 blocks/CU anyway. amdgpu_waves_per_eu(4,4) pins
// the target at 4 waves/EU -> 128-VGPR budget. Also: explicit fmaf.

#define TSTEPS 12
#define SEQ 64
#define AROW 132

__device__ __forceinline__ float fsig(float z) {
    z = fminf(fmaxf(z, -30.f), 30.f);
    return 1.f / (1.f + __expf(-z));
}
__device__ __forceinline__ float ftanh(float z) {
    z = fminf(fmaxf(z, -15.f), 15.f);
    float e = __expf(2.f * z);
    return 1.f - 2.f / (e + 1.f);
}

// ---- workspace layout (floats) ----
// [0, 256)          W0x  : 64 float4 (Wu0[0][c], Wu0[1][c], Wc0[0][c], Wc0[1][c])
// [256, 8448)       W0h  : 16 k4-rows x 128 float4  [u cols | c cols]
// [8448, 8960)      pad
// [8960, 25344)     W1h  : 32 k4-rows x 128 float4
// [25344, 25856)    pad
// [25856, 25984)    bu0 | bc0
// [25984, 26112)    bu1 | bc1
// [26112, 26176)    Wo
// [26176]           bo

__global__ void pack_weights(const float* __restrict__ Wu0, const float* __restrict__ bu0,
                             const float* __restrict__ Wc0, const float* __restrict__ bc0,
                             const float* __restrict__ Wu1, const float* __restrict__ bu1,
                             const float* __restrict__ Wc1, const float* __restrict__ bc1,
                             const float* __restrict__ Wo, const float* __restrict__ bo,
                             float* __restrict__ Wp) {
    const int tid = blockIdx.x * blockDim.x + threadIdx.x;
    const int nthr = gridDim.x * blockDim.x;
    float4* W0x = (float4*)Wp;
    float4* W0h = (float4*)(Wp + 256);
    float4* W1h = (float4*)(Wp + 8960);

    if (tid < 64) {
        W0x[tid] = make_float4(Wu0[tid], Wu0[64 + tid], Wc0[tid], Wc0[64 + tid]);
    }
    for (int i = tid; i < 16 * 128; i += nthr) {
        const int k4 = i >> 7, col = i & 127;
        const float* G = (col < 64) ? Wu0 : Wc0;
        const int cc = col & 63;
        const int r = 2 + k4 * 4;
        W0h[i] = make_float4(G[r * 64 + cc], G[(r + 1) * 64 + cc],
                             G[(r + 2) * 64 + cc], G[(r + 3) * 64 + cc]);
    }
    for (int i = tid; i < 32 * 128; i += nthr) {
        const int k4 = i >> 7, col = i & 127;
        const float* G = (col < 64) ? Wu1 : Wc1;
        const int cc = col & 63;
        const int r = k4 * 4;
        W1h[i] = make_float4(G[r * 64 + cc], G[(r + 1) * 64 + cc],
                             G[(r + 2) * 64 + cc], G[(r + 3) * 64 + cc]);
    }
    for (int i = tid; i < 512; i += nthr) { Wp[8448 + i] = 0.f; Wp[25344 + i] = 0.f; }
    if (tid < 128) Wp[25856 + tid] = (tid < 64) ? bu0[tid] : bc0[tid - 64];
    if (tid >= 128 && tid < 256) {
        const int q = tid - 128;
        Wp[25984 + q] = (q < 64) ? bu1[q] : bc1[q - 64];
    }
    if (tid >= 256 && tid < 320) Wp[26112 + (tid - 256)] = Wo[tid - 256];
    if (tid == 320) Wp[26176] = bo[0];
}

// ---- scalarized FMA machinery (no local arrays, explicit fmaf) ----
#define DOT4(acc, av, wv) { \
    acc = __builtin_fmaf(av.x, wv.x, acc); acc = __builtin_fmaf(av.y, wv.y, acc); \
    acc = __builtin_fmaf(av.z, wv.z, acc); acc = __builtin_fmaf(av.w, wv.w, acc); }

#define FMAROW(M, av) \
    DOT4(aU##M##0, av, w0) DOT4(aU##M##1, av, w1) DOT4(aU##M##2, av, w2) DOT4(aU##M##3, av, w3) \
    DOT4(aC##M##0, av, w4) DOT4(aC##M##1, av, w5) DOT4(aC##M##2, av, w6) DOT4(aC##M##3, av, w7)

#define KCHUNK(WQ, AOFF) { \
    const float4 w0 = (WQ)[0],  w1 = (WQ)[1],  w2 = (WQ)[2],  w3 = (WQ)[3]; \
    const float4 w4 = (WQ)[64], w5 = (WQ)[65], w6 = (WQ)[66], w7 = (WQ)[67]; \
    const float4 a0v = *(const float4*)&A[srow0 + (AOFF)]; \
    const float4 a1v = *(const float4*)&A[srow1 + (AOFF)]; \
    const float4 a2v = *(const float4*)&A[srow2 + (AOFF)]; \
    const float4 a3v = *(const float4*)&A[srow3 + (AOFF)]; \
    FMAROW(0, a0v) FMAROW(1, a1v) FMAROW(2, a2v) FMAROW(3, a3v) }

#define AINIT(BU_OFF, BC_OFF) { \
    const float4 bu = *(const float4*)&bsh[(BU_OFF) + jcol]; \
    const float4 bc = *(const float4*)&bsh[(BC_OFF) + jcol]; \
    aU00 = bu.x; aU01 = bu.y; aU02 = bu.z; aU03 = bu.w; \
    aU10 = bu.x; aU11 = bu.y; aU12 = bu.z; aU13 = bu.w; \
    aU20 = bu.x; aU21 = bu.y; aU22 = bu.z; aU23 = bu.w; \
    aU30 = bu.x; aU31 = bu.y; aU32 = bu.z; aU33 = bu.w; \
    aC00 = bc.x; aC01 = bc.y; aC02 = bc.z; aC03 = bc.w; \
    aC10 = bc.x; aC11 = bc.y; aC12 = bc.z; aC13 = bc.w; \
    aC20 = bc.x; aC21 = bc.y; aC22 = bc.z; aC23 = bc.w; \
    aC30 = bc.x; aC31 = bc.y; aC32 = bc.z; aC33 = bc.w; }

#define XPART(M) { \
    const int s_ = sg + 16 * M; \
    const float x0v = xs[2 * s_], x1v = xs[2 * s_ + 1]; \
    aU##M##0 = __builtin_fmaf(x0v, wx0.x, __builtin_fmaf(x1v, wx0.y, aU##M##0)); \
    aC##M##0 = __builtin_fmaf(x0v, wx0.z, __builtin_fmaf(x1v, wx0.w, aC##M##0)); \
    aU##M##1 = __builtin_fmaf(x0v, wx1.x, __builtin_fmaf(x1v, wx1.y, aU##M##1)); \
    aC##M##1 = __builtin_fmaf(x0v, wx1.z, __builtin_fmaf(x1v, wx1.w, aC##M##1)); \
    aU##M##2 = __builtin_fmaf(x0v, wx2.x, __builtin_fmaf(x1v, wx2.y, aU##M##2)); \
    aC##M##2 = __builtin_fmaf(x0v, wx2.z, __builtin_fmaf(x1v, wx2.w, aC##M##2)); \
    aU##M##3 = __builtin_fmaf(x0v, wx3.x, __builtin_fmaf(x1v, wx3.y, aU##M##3)); \
    aC##M##3 = __builtin_fmaf(x0v, wx3.z, __builtin_fmaf(x1v, wx3.w, aC##M##3)); }

#define HUPDATE(M, COLBASE) { \
    const float4 ho = *(const float4*)&A[srow##M + (COLBASE)]; \
    float u_, c_; \
    u_ = fsig(aU##M##0); c_ = ftanh(aC##M##0); hn##M.x = __builtin_fmaf(u_, ho.x, (1.f - u_) * c_); \
    u_ = fsig(aU##M##1); c_ = ftanh(aC##M##1); hn##M.y = __builtin_fmaf(u_, ho.y, (1.f - u_) * c_); \
    u_ = fsig(aU##M##2); c_ = ftanh(aC##M##2); hn##M.z = __builtin_fmaf(u_, ho.z, (1.f - u_) * c_); \
    u_ = fsig(aU##M##3); c_ = ftanh(aC##M##3); hn##M.w = __builtin_fmaf(u_, ho.w, (1.f - u_) * c_); }

__global__ __attribute__((amdgpu_flat_work_group_size(256, 256),
                          amdgpu_waves_per_eu(4, 4)))
void dcrnn_main(const float* __restrict__ x,
                const float* __restrict__ Wp,
                float* __restrict__ out) {
    __shared__ float A[SEQ * AROW];   // [seq][0..63]=h0, [64..127]=h1, pad
    __shared__ float xs[SEQ * 2];
    __shared__ float bsh[324];        // bu0|bc0 (128) | bu1|bc1 (128) | Wo (64) | bo

    const int tid = threadIdx.x;
    const int sg = tid & 15;        // seq group: seqs sg, sg+16, sg+32, sg+48
    const int jg = tid >> 4;        // col group 0..15
    const int jcol = jg * 4;

    const int s0 = blockIdx.x * SEQ;
    const int b = s0 >> 11;
    const int n0 = s0 & 2047;

    const float4* W0x = (const float4*)Wp;
    const float4* W0h = (const float4*)(Wp + 256);
    const float4* W1h = (const float4*)(Wp + 8960);

    for (int i = tid; i < SEQ * AROW; i += 256) A[i] = 0.f;
    bsh[tid] = Wp[25856 + tid];
    if (tid < 65) bsh[256 + tid] = Wp[26112 + tid];

    const float* xb = x + (size_t)(b * TSTEPS) * 4096 + (size_t)n0 * 2;

    const int srow0 = (sg + 0)  * AROW;
    const int srow1 = (sg + 16) * AROW;
    const int srow2 = (sg + 32) * AROW;
    const int srow3 = (sg + 48) * AROW;

    float aU00, aU01, aU02, aU03, aU10, aU11, aU12, aU13;
    float aU20, aU21, aU22, aU23, aU30, aU31, aU32, aU33;
    float aC00, aC01, aC02, aC03, aC10, aC11, aC12, aC13;
    float aC20, aC21, aC22, aC23, aC30, aC31, aC32, aC33;
    float4 hn0, hn1, hn2, hn3;

#pragma unroll 1
    for (int t = 0; t < TSTEPS; ++t) {
        if (tid < 32) ((float4*)xs)[tid] = ((const float4*)(xb + t * 4096))[tid];
        __syncthreads();  // (1) x staged; prev-step h writes (+ init) visible

        // ================= layer 0 : [x|h0] @ {Wu0,Wc0} =================
        AINIT(0, 64)
        {
            const float4 wx0 = W0x[jcol + 0], wx1 = W0x[jcol + 1];
            const float4 wx2 = W0x[jcol + 2], wx3 = W0x[jcol + 3];
            XPART(0) XPART(1) XPART(2) XPART(3)
        }
        {
            const float4* wq = W0h + jcol;
#pragma unroll 4
            for (int k4 = 0; k4 < 16; ++k4) {
                KCHUNK(wq, k4 * 4)
                wq += 128;
            }
        }
        HUPDATE(0, jcol) HUPDATE(1, jcol) HUPDATE(2, jcol) HUPDATE(3, jcol)
        __syncthreads();  // (2) all reads of h0_old done
        *(float4*)&A[srow0 + jcol] = hn0;
        *(float4*)&A[srow1 + jcol] = hn1;
        *(float4*)&A[srow2 + jcol] = hn2;
        *(float4*)&A[srow3 + jcol] = hn3;
        __syncthreads();  // (3) h0_new visible

        // ================= layer 1 : [h0|h1] @ {Wu1,Wc1} =================
        AINIT(128, 192)
        {
            const float4* wq = W1h + jcol;
#pragma unroll 4
            for (int k4 = 0; k4 < 32; ++k4) {
                KCHUNK(wq, k4 * 4)
                wq += 128;
            }
        }
        HUPDATE(0, 64 + jcol) HUPDATE(1, 64 + jcol) HUPDATE(2, 64 + jcol) HUPDATE(3, 64 + jcol)
        __syncthreads();  // (4) all reads of h1_old done
        *(float4*)&A[srow0 + 64 + jcol] = hn0;
        *(float4*)&A[srow1 + 64 + jcol] = hn1;
        *(float4*)&A[srow2 + 64 + jcol] = hn2;
        *(float4*)&A[srow3 + 64 + jcol] = hn3;
        // next-iteration barrier (1) makes h1_new visible before anyone reads it
    }

    __syncthreads();  // h1 final visible
    if (tid < 64) {
        float acc = bsh[320];
#pragma unroll
        for (int k4 = 0; k4 < 16; ++k4) {
            const float4 h4 = *(const float4*)&A[tid * AROW + 64 + k4 * 4];
            const float4 w4 = *(const float4*)&bsh[256 + k4 * 4];
            acc = __builtin_fmaf(h4.x, w4.x, acc); acc = __builtin_fmaf(h4.y, w4.y, acc);
            acc = __builtin_fmaf(h4.z, w4.z, acc); acc = __builtin_fmaf(h4.w, w4.w, acc);
        }
        out[s0 + tid] = acc;
    }
}

extern "C" void kernel_launch(void* const* d_in, const int* in_sizes, int n_in,
                              void* d_out, int out_size, void* d_ws, size_t ws_size,
                              hipStream_t stream) {
    const float* x   = (const float*)d_in[0];
    // d_in[1] supports, d_in[2] Wr0, d_in[3] br0 : dead code in reference
    const float* Wu0 = (const float*)d_in[4];
    const float* bu0 = (const float*)d_in[5];
    const float* Wc0 = (const float*)d_in[6];
    const float* bc0 = (const float*)d_in[7];
    // d_in[8] Wd0, d_in[9] bd0, d_in[10] Wr1, d_in[11] br1 : dead
    const float* Wu1 = (const float*)d_in[12];
    const float* bu1 = (const float*)d_in[13];
    const float* Wc1 = (const float*)d_in[14];
    const float* bc1 = (const float*)d_in[15];
    // d_in[16] Wd1, d_in[17] bd1 : dead
    const float* Wo  = (const float*)d_in[18];
    const float* bo  = (const float*)d_in[19];

    float* Wp = (float*)d_ws;  // ~105 KB

    hipLaunchKernelGGL(pack_weights, dim3(2), dim3(256), 0, stream,
                       Wu0, bu0, Wc0, bc0, Wu1, bu1, Wc1, bc1, Wo, bo, Wp);
    hipLaunchKernelGGL(dcrnn_main, dim3(65536 / SEQ), dim3(256), 0, stream,
                       x, Wp, (float*)d_out);
}

// Round 7
// 635.072 us; speedup vs baseline: 1.5777x; 1.2052x over previous
//
#include <hip/hip_runtime.h>

// DCRNN (DCE'd): 65536 independent sequences, 12 steps, 2-layer GRU-lite, H=64.
// fp32 vector-ALU implementation (no fp32 MFMA on CDNA4).
//
// Round-7 restructure: SGPR-weight layout.
//   - wave w owns output cols [w*16, w*16+16) for BOTH u and c gates (32 acc).
//   - lane = sequence (64 seqs/block). Weight W[k][col] is lane-uniform ->
//     readfirstlane'd base -> s_load into SGPRs -> v_fmac v,s,v. Weights never
//     occupy VGPRs; no VMEM in the inner loop.
//   - h state transposed in LDS: A[k][seq] (k=0..63 h0, 64..127 h1). One
//     ds_read_b32 per k feeds 32 FMAs; 2 lanes/bank = conflict-free.
//   - 3 barriers/step (h1 writes are disjoint from next-step L0 reads).
// Rationale: round-6 counters showed real VALU util ~34% (VALUBusy 69% is the
// gfx94x SIMD-16 formula, 2x inflated) -> latency-stalled on per-thread VMEM
// weight loads under a 64-VGPR file. This moves the weight stream to the
// scalar pipe and cuts LDS/VGPR pressure.

#define TSTEPS 12

__device__ __forceinline__ float fsig(float z) {
    z = fminf(fmaxf(z, -30.f), 30.f);
    return 1.f / (1.f + __expf(-z));
}
__device__ __forceinline__ float ftanh(float z) {
    z = fminf(fmaxf(z, -15.f), 15.f);
    float e = __expf(2.f * z);
    return 1.f - 2.f / (e + 1.f);
}

// ---- workspace layout (floats) ----
// [0, 256)        L0x : [k(2)][w(4)][32]   (j<16: Wu0[k][w*16+j], else Wc0)
// [256, 8448)     L0h : [k(64)][w(4)][32]  rows 2+k of Wu0/Wc0
// [8448, 24832)   L1h : [k(128)][w(4)][32] rows of Wu1/Wc1
// [24832, 24960)  B0  : [w(4)][32]  bu0|bc0
// [24960, 25088)  B1  : [w(4)][32]  bu1|bc1
// [25088, 25152)  Wo  : 64
// [25152]         bo

__global__ void pack_weights(const float* __restrict__ Wu0, const float* __restrict__ bu0,
                             const float* __restrict__ Wc0, const float* __restrict__ bc0,
                             const float* __restrict__ Wu1, const float* __restrict__ bu1,
                             const float* __restrict__ Wc1, const float* __restrict__ bc1,
                             const float* __restrict__ Wo, const float* __restrict__ bo,
                             float* __restrict__ Wp) {
    const int tid = blockIdx.x * blockDim.x + threadIdx.x;
    const int nthr = gridDim.x * blockDim.x;
    for (int i = tid; i < 256; i += nthr) {
        const int k = i >> 7, r = i & 127, wv = r >> 5, j = r & 31;
        const int col = wv * 16 + (j & 15);
        Wp[i] = (j < 16) ? Wu0[k * 64 + col] : Wc0[k * 64 + col];
    }
    for (int i = tid; i < 8192; i += nthr) {
        const int k = i >> 7, r = i & 127, wv = r >> 5, j = r & 31;
        const int col = wv * 16 + (j & 15);
        Wp[256 + i] = (j < 16) ? Wu0[(2 + k) * 64 + col] : Wc0[(2 + k) * 64 + col];
    }
    for (int i = tid; i < 16384; i += nthr) {
        const int k = i >> 7, r = i & 127, wv = r >> 5, j = r & 31;
        const int col = wv * 16 + (j & 15);
        Wp[8448 + i] = (j < 16) ? Wu1[k * 64 + col] : Wc1[k * 64 + col];
    }
    for (int i = tid; i < 128; i += nthr) {
        const int wv = i >> 5, j = i & 31;
        const int col = wv * 16 + (j & 15);
        Wp[24832 + i] = (j < 16) ? bu0[col] : bc0[col];
        Wp[24960 + i] = (j < 16) ? bu1[col] : bc1[col];
    }
    for (int i = tid; i < 64; i += nthr) Wp[25088 + i] = Wo[i];
    if (tid == 0) Wp[25152] = bo[0];
}

// ---- 16-column macro machinery (all names, no arrays) ----
#define REP16(X) X(0) X(1) X(2) X(3) X(4) X(5) X(6) X(7) \
                 X(8) X(9) X(10) X(11) X(12) X(13) X(14) X(15)

#define INITJ(J) zu##J = bp_[J]; zc##J = bp_[16 + J];
#define FMAJ(J)  zu##J = __builtin_fmaf(hk_, wk_[J], zu##J); \
                 zc##J = __builtin_fmaf(hk_, wk_[16 + J], zc##J);
#define XPJ(J)   zu##J = __builtin_fmaf(xv.x, wx_[J], zu##J); \
                 zu##J = __builtin_fmaf(xv.y, wx_[128 + J], zu##J); \
                 zc##J = __builtin_fmaf(xv.x, wx_[16 + J], zc##J); \
                 zc##J = __builtin_fmaf(xv.y, wx_[128 + 16 + J], zc##J);
#define ACTJ(J)  { const float u_ = fsig(zu##J); const float c_ = ftanh(zc##J); \
                   zu##J = __builtin_fmaf(u_, hb_[(J) * 64], (1.f - u_) * c_); }
#define STJ(J)   hb_[(J) * 64] = zu##J;
#define KSTEP(AR, WB, KK) { const float hk_ = (AR)[(KK) * 64]; \
                            const float* wk_ = (WB) + (size_t)(KK) * 128; REP16(FMAJ) }
#define POJ(J)   part = __builtin_fmaf(zu##J, wo_[J], part);

__global__ __launch_bounds__(256, 4) void dcrnn_main(const float* __restrict__ x,
                                                     const float* __restrict__ Wp,
                                                     float* __restrict__ out) {
    __shared__ float A[128 * 64];   // A[k][seq]: k 0..63 = h0, 64..127 = h1
    __shared__ float P[4 * 64];     // output partials per wave

    const int tid = threadIdx.x;
    const int lane = tid & 63;                                   // sequence
    const int w = __builtin_amdgcn_readfirstlane(tid >> 6);      // wave id (uniform)

    const int s0 = blockIdx.x * 64;
    const int b = s0 >> 11;
    const int n0 = s0 & 2047;

    const float* Wxw = Wp + w * 32;            // L0x  [k][w][32]
    const float* W0w = Wp + 256 + w * 32;      // L0h
    const float* W1w = Wp + 8448 + w * 32;     // L1h
    const float* B0w = Wp + 24832 + w * 32;
    const float* B1w = Wp + 24960 + w * 32;

    for (int i = tid; i < 128 * 64; i += 256) A[i] = 0.f;
    __syncthreads();

    const float* Arow = A + lane;
    const float* xlane = x + (size_t)(b * TSTEPS) * 4096 + (size_t)(n0 + lane) * 2;
    float* hb0 = &A[(w * 16) * 64 + lane];        // this wave's h0 cols
    float* hb1 = &A[(64 + w * 16) * 64 + lane];   // this wave's h1 cols

    float zu0, zu1, zu2, zu3, zu4, zu5, zu6, zu7;
    float zu8, zu9, zu10, zu11, zu12, zu13, zu14, zu15;
    float zc0, zc1, zc2, zc3, zc4, zc5, zc6, zc7;
    float zc8, zc9, zc10, zc11, zc12, zc13, zc14, zc15;

#pragma unroll 1
    for (int t = 0; t < TSTEPS; ++t) {
        const float2 xv = *(const float2*)(xlane + t * 4096);

        // ===== layer 0: z = b0 + h0_old @ W0h + x @ W0x =====
        { const float* bp_ = B0w; REP16(INITJ) }
#pragma unroll 1
        for (int k = 0; k < 64; k += 4) {
            KSTEP(Arow, W0w, k + 0)
            KSTEP(Arow, W0w, k + 1)
            KSTEP(Arow, W0w, k + 2)
            KSTEP(Arow, W0w, k + 3)
        }
        { const float* wx_ = Wxw; REP16(XPJ) }
        { const float* hb_ = hb0; REP16(ACTJ) }   // zuJ <- h0_new
        __syncthreads();  // (1) all L0 reads of h0_old done
        { float* hb_ = hb0; REP16(STJ) }
        __syncthreads();  // (2) h0_new visible

        // ===== layer 1: z = b1 + [h0_new|h1_old] @ W1h =====
        { const float* bp_ = B1w; REP16(INITJ) }
#pragma unroll 1
        for (int k = 0; k < 128; k += 4) {
            KSTEP(Arow, W1w, k + 0)
            KSTEP(Arow, W1w, k + 1)
            KSTEP(Arow, W1w, k + 2)
            KSTEP(Arow, W1w, k + 3)
        }
        { const float* hb_ = hb1; REP16(ACTJ) }   // zuJ <- h1_new
        __syncthreads();  // (3) all L1 reads (h0_new, h1_old) done
        { float* hb_ = hb1; REP16(STJ) }
        // no 4th barrier: next-step L0 reads h0 only (disjoint); L1 reads of
        // h1 are separated by next step's barriers (1)+(2).
    }

    // ===== epilogue: out = h1 @ Wo + bo  (h1 still in zu regs) =====
    float part = 0.f;
    { const float* wo_ = Wp + 25088 + w * 16; REP16(POJ) }
    P[w * 64 + lane] = part;
    __syncthreads();
    if (tid < 64) {
        out[s0 + tid] = Wp[25152] + P[tid] + P[64 + tid] + P[128 + tid] + P[192 + tid];
    }
}

extern "C" void kernel_launch(void* const* d_in, const int* in_sizes, int n_in,
                              void* d_out, int out_size, void* d_ws, size_t ws_size,
                              hipStream_t stream) {
    const float* x   = (const float*)d_in[0];
    // d_in[1] supports, d_in[2] Wr0, d_in[3] br0 : dead code in reference
    const float* Wu0 = (const float*)d_in[4];
    const float* bu0 = (const float*)d_in[5];
    const float* Wc0 = (const float*)d_in[6];
    const float* bc0 = (const float*)d_in[7];
    // d_in[8] Wd0, d_in[9] bd0, d_in[10] Wr1, d_in[11] br1 : dead
    const float* Wu1 = (const float*)d_in[12];
    const float* bu1 = (const float*)d_in[13];
    const float* Wc1 = (const float*)d_in[14];
    const float* bc1 = (const float*)d_in[15];
    // d_in[16] Wd1, d_in[17] bd1 : dead
    const float* Wo  = (const float*)d_in[18];
    const float* bo  = (const float*)d_in[19];

    float* Wp = (float*)d_ws;  // ~101 KB

    hipLaunchKernelGGL(pack_weights, dim3(64), dim3(256), 0, stream,
                       Wu0, bu0, Wc0, bc0, Wu1, bu1, Wc1, bc1, Wo, bo, Wp);
    hipLaunchKernelGGL(dcrnn_main, dim3(65536 / 64), dim3(256), 0, stream,
                       x, Wp, (float*)d_out);
}

// Round 8
// 589.065 us; speedup vs baseline: 1.7009x; 1.0781x over previous
//
#include <hip/hip_runtime.h>

// DCRNN (DCE'd): 65536 independent sequences, 12 steps, 2-layer GRU-lite, H=64.
// fp32 vector-ALU implementation (no fp32 MFMA on CDNA4).
//
// Round-8: amortize SMEM weight stream over 2 sequences per lane.
//   - 512 threads/block (8 waves), 128 seqs/block. Wave w owns cols
//     [w*8, w*8+8) for u AND c (32 accumulators = 8 cols x 2 gates x 2 seqs).
//   - h state in LDS pair-interleaved: A[k][2*lane+p] -> one ds_read_b64 per
//     k-step serves both seqs (2-way pair aliasing = free).
//   - weights lane-uniform: [k][w][16] pack -> one s_load_dwordx16 per k-step
//     feeds 32 FMAs (was 32 floats / 32 FMAs in round 7 -> halved SMEM, the
//     lgkmcnt(0) SMEM+LDS drain per FMA halves).
//   - 2 blocks/CU (69.6 KB LDS) = 16 waves/CU for stall hiding.

#define TSTEPS 12

__device__ __forceinline__ float fsig(float z) {
    z = fminf(fmaxf(z, -30.f), 30.f);
    return 1.f / (1.f + __expf(-z));
}
__device__ __forceinline__ float ftanh(float z) {
    z = fminf(fmaxf(z, -15.f), 15.f);
    float e = __expf(2.f * z);
    return 1.f - 2.f / (e + 1.f);
}

// ---- workspace layout (floats) ----
// [0, 8192)       L0h : [k(64)][w(8)][16]  (j<8: Wu0[2+k][w*8+j], else Wc0)
// [8192, 8448)    L0x : [k(2)][w(8)][16]   rows 0..1 of Wu0/Wc0
// [8448, 24832)   L1h : [k(128)][w(8)][16] rows of Wu1/Wc1
// [24832, 24960)  B0  : [w(8)][16]  bu0|bc0
// [24960, 25088)  B1  : [w(8)][16]  bu1|bc1
// [25088, 25152)  Wo  : 64
// [25152]         bo

__global__ void pack_weights(const float* __restrict__ Wu0, const float* __restrict__ bu0,
                             const float* __restrict__ Wc0, const float* __restrict__ bc0,
                             const float* __restrict__ Wu1, const float* __restrict__ bu1,
                             const float* __restrict__ Wc1, const float* __restrict__ bc1,
                             const float* __restrict__ Wo, const float* __restrict__ bo,
                             float* __restrict__ Wp) {
    const int tid = blockIdx.x * blockDim.x + threadIdx.x;
    const int nthr = gridDim.x * blockDim.x;
    for (int i = tid; i < 8192; i += nthr) {
        const int k = i >> 7, r = i & 127, wv = r >> 4, j = r & 15;
        const int col = wv * 8 + (j & 7);
        Wp[i] = (j < 8) ? Wu0[(2 + k) * 64 + col] : Wc0[(2 + k) * 64 + col];
    }
    for (int i = tid; i < 256; i += nthr) {
        const int k = i >> 7, r = i & 127, wv = r >> 4, j = r & 15;
        const int col = wv * 8 + (j & 7);
        Wp[8192 + i] = (j < 8) ? Wu0[k * 64 + col] : Wc0[k * 64 + col];
    }
    for (int i = tid; i < 16384; i += nthr) {
        const int k = i >> 7, r = i & 127, wv = r >> 4, j = r & 15;
        const int col = wv * 8 + (j & 7);
        Wp[8448 + i] = (j < 8) ? Wu1[k * 64 + col] : Wc1[k * 64 + col];
    }
    for (int i = tid; i < 128; i += nthr) {
        const int wv = i >> 4, j = i & 15;
        const int col = wv * 8 + (j & 7);
        Wp[24832 + i] = (j < 8) ? bu0[col] : bc0[col];
        Wp[24960 + i] = (j < 8) ? bu1[col] : bc1[col];
    }
    for (int i = tid; i < 64; i += nthr) Wp[25088 + i] = Wo[i];
    if (tid == 0) Wp[25152] = bo[0];
}

// ---- 8-column x 2-seq macro machinery (no arrays) ----
#define REP8(X) X(0) X(1) X(2) X(3) X(4) X(5) X(6) X(7)

#define INITJ(J) zu##J##0 = bp_[J]; zu##J##1 = bp_[J]; \
                 zc##J##0 = bp_[8 + J]; zc##J##1 = bp_[8 + J];

#define FMAJ(J) \
    zu##J##0 = __builtin_fmaf(hv.x, wk_[J], zu##J##0); \
    zu##J##1 = __builtin_fmaf(hv.y, wk_[J], zu##J##1); \
    zc##J##0 = __builtin_fmaf(hv.x, wk_[8 + J], zc##J##0); \
    zc##J##1 = __builtin_fmaf(hv.y, wk_[8 + J], zc##J##1);

#define KSTEP(WB, KK) { \
    const float2 hv = *(const float2*)(Aptr + (size_t)(KK) * 128); \
    const float* wk_ = (WB) + (size_t)(KK) * 128; \
    REP8(FMAJ) }

#define XPJ(J) \
    zu##J##0 = __builtin_fmaf(xv.x, wx_[J], __builtin_fmaf(xv.y, wx_[128 + J], zu##J##0)); \
    zu##J##1 = __builtin_fmaf(xv.z, wx_[J], __builtin_fmaf(xv.w, wx_[128 + J], zu##J##1)); \
    zc##J##0 = __builtin_fmaf(xv.x, wx_[8 + J], __builtin_fmaf(xv.y, wx_[136 + J], zc##J##0)); \
    zc##J##1 = __builtin_fmaf(xv.z, wx_[8 + J], __builtin_fmaf(xv.w, wx_[136 + J], zc##J##1));

#define ACTJ(J) { \
    const float2 ho = *(const float2*)(hb_ + (J) * 128); \
    float u_, c_; \
    u_ = fsig(zu##J##0); c_ = ftanh(zc##J##0); \
    zu##J##0 = __builtin_fmaf(u_, ho.x, (1.f - u_) * c_); \
    u_ = fsig(zu##J##1); c_ = ftanh(zc##J##1); \
    zu##J##1 = __builtin_fmaf(u_, ho.y, (1.f - u_) * c_); }

#define STJ(J) *(float2*)(hb_ + (J) * 128) = make_float2(zu##J##0, zu##J##1);

#define POJ(J) part0 = __builtin_fmaf(zu##J##0, wo_[J], part0); \
               part1 = __builtin_fmaf(zu##J##1, wo_[J], part1);

__global__ __launch_bounds__(512, 4) void dcrnn_main(const float* __restrict__ x,
                                                     const float* __restrict__ Wp,
                                                     float* __restrict__ out) {
    __shared__ float A[128 * 128];  // A[k][2*lane+p]: k 0..63 = h0, 64..127 = h1
    __shared__ float P[8 * 128];    // per-wave output partials

    const int tid = threadIdx.x;
    const int lane = tid & 63;
    const int w = __builtin_amdgcn_readfirstlane(tid >> 6);  // wave id, uniform

    const int s0 = blockIdx.x * 128;
    const int b = s0 >> 11;
    const int n0 = s0 & 2047;

    const float* W0w = Wp + w * 16;           // L0h [k][w][16]
    const float* Wxw = Wp + 8192 + w * 16;    // L0x
    const float* W1w = Wp + 8448 + w * 16;    // L1h
    const float* B0w = Wp + 24832 + w * 16;
    const float* B1w = Wp + 24960 + w * 16;

    for (int i = tid; i < 128 * 128; i += 512) A[i] = 0.f;
    __syncthreads();

    const float* Aptr0 = A + 2 * lane;                    // layer-0 k base
    float* hb0 = A + (size_t)(w * 8) * 128 + 2 * lane;    // this wave's h0 cols
    float* hb1 = A + (size_t)(64 + w * 8) * 128 + 2 * lane;

    const float* xlane = x + (size_t)(b * TSTEPS) * 4096 + (size_t)(n0 + 2 * lane) * 2;

    float zu00, zu01, zu10, zu11, zu20, zu21, zu30, zu31;
    float zu40, zu41, zu50, zu51, zu60, zu61, zu70, zu71;
    float zc00, zc01, zc10, zc11, zc20, zc21, zc30, zc31;
    float zc40, zc41, zc50, zc51, zc60, zc61, zc70, zc71;

#pragma unroll 1
    for (int t = 0; t < TSTEPS; ++t) {
        const float4 xv = *(const float4*)(xlane + (size_t)t * 4096);

        // ===== layer 0: z = b0 + h0_old @ W0h + x @ W0x =====
        { const float* bp_ = B0w; REP8(INITJ) }
        {
            const float* Aptr = Aptr0;
#pragma unroll 1
            for (int k = 0; k < 64; k += 4) {
                KSTEP(W0w, k + 0)
                KSTEP(W0w, k + 1)
                KSTEP(W0w, k + 2)
                KSTEP(W0w, k + 3)
            }
        }
        { const float* wx_ = Wxw; REP8(XPJ) }
        { const float* hb_ = hb0; REP8(ACTJ) }   // zuJp <- h0_new
        __syncthreads();  // (1) all reads of h0_old done
        { float* hb_ = hb0; REP8(STJ) }
        __syncthreads();  // (2) h0_new visible

        // ===== layer 1: z = b1 + [h0_new|h1_old] @ W1h =====
        { const float* bp_ = B1w; REP8(INITJ) }
        {
            const float* Aptr = Aptr0;
#pragma unroll 1
            for (int k = 0; k < 128; k += 4) {
                KSTEP(W1w, k + 0)
                KSTEP(W1w, k + 1)
                KSTEP(W1w, k + 2)
                KSTEP(W1w, k + 3)
            }
        }
        { const float* hb_ = hb1; REP8(ACTJ) }   // zuJp <- h1_new
        __syncthreads();  // (3) all layer-1 reads (h0_new, h1_old) done
        { float* hb_ = hb1; REP8(STJ) }
        // no 4th barrier: next-step layer 0 never reads h1; h1 reads at t+1
        // happen after t+1's barriers (1)+(2).
    }

    // ===== epilogue: out = h1 @ Wo + bo  (h1 still in zu regs) =====
    float part0 = 0.f, part1 = 0.f;
    { const float* wo_ = Wp + 25088 + w * 8; REP8(POJ) }
    *(float2*)&P[w * 128 + 2 * lane] = make_float2(part0, part1);
    __syncthreads();
    if (tid < 128) {
        float acc = Wp[25152];
#pragma unroll
        for (int wv = 0; wv < 8; ++wv) acc += P[wv * 128 + tid];
        out[s0 + tid] = acc;
    }
}

extern "C" void kernel_launch(void* const* d_in, const int* in_sizes, int n_in,
                              void* d_out, int out_size, void* d_ws, size_t ws_size,
                              hipStream_t stream) {
    const float* x   = (const float*)d_in[0];
    // d_in[1] supports, d_in[2] Wr0, d_in[3] br0 : dead code in reference
    const float* Wu0 = (const float*)d_in[4];
    const float* bu0 = (const float*)d_in[5];
    const float* Wc0 = (const float*)d_in[6];
    const float* bc0 = (const float*)d_in[7];
    // d_in[8] Wd0, d_in[9] bd0, d_in[10] Wr1, d_in[11] br1 : dead
    const float* Wu1 = (const float*)d_in[12];
    const float* bu1 = (const float*)d_in[13];
    const float* Wc1 = (const float*)d_in[14];
    const float* bc1 = (const float*)d_in[15];
    // d_in[16] Wd1, d_in[17] bd1 : dead
    const float* Wo  = (const float*)d_in[18];
    const float* bo  = (const float*)d_in[19];

    float* Wp = (float*)d_ws;  // ~101 KB

    hipLaunchKernelGGL(pack_weights, dim3(64), dim3(256), 0, stream,
                       Wu0, bu0, Wc0, bc0, Wu1, bu1, Wc1, bc1, Wo, bo, Wp);
    hipLaunchKernelGGL(dcrnn_main, dim3(65536 / 128), dim3(512), 0, stream,
                       x, Wp, (float*)d_out);
}